// Round 7
// baseline (619.915 us; speedup 1.0000x reference)
//
#include <hip/hip_runtime.h>

#define CC   128      // channels
#define GG   4        // gates
#define BB   16       // batch
#define LL   32768    // length
#define TL   128      // l-positions per tile
#define NTL  256      // tiles per batch (LL/TL)
#define EPSV 1e-5f
#define WROW 136      // ushorts per LDS row = 272 B (breaks power-of-2 bank aliasing)

typedef short short8 __attribute__((ext_vector_type(8)));
typedef float f32x16 __attribute__((ext_vector_type(16)));

__device__ inline unsigned short f2bf(float f) {   // RNE float->bf16
    union { float f; unsigned int u; } v; v.f = f;
    unsigned int r = (v.u + 0x7FFF + ((v.u >> 16) & 1)) >> 16;
    return (unsigned short)r;
}
__device__ inline float bf2f(unsigned short h) {
    union { unsigned int u; float f; } v; v.u = ((unsigned int)h) << 16; return v.f;
}

// One fused kernel: stage x tile (only HBM read of x) + pool partial + gate
// sync (per-batch counter) + gate/affine + MFMA + NT store.
__global__ __launch_bounds__(256, 4) void fused_kernel(const float* __restrict__ x,
                                                       const float* __restrict__ gumbel,
                                                       const float* __restrict__ w_gate,
                                                       const float* __restrict__ conv_b,
                                                       const float* __restrict__ bn_w,
                                                       const float* __restrict__ bn_b,
                                                       const float* __restrict__ rmean,
                                                       const float* __restrict__ rvar,
                                                       const float* __restrict__ conv_w,
                                                       float* __restrict__ pool,
                                                       int* __restrict__ counter,
                                                       int* __restrict__ ticket_ctr,
                                                       float* __restrict__ out) {
    __shared__ unsigned short xlds[TL * WROW];   // 34,816 B
    __shared__ float scratch[1024];              // partials[8][128] -> pl/sA/sT/logits
    __shared__ int smisc[2];                     // [0]=ticket, [1]=gate idx

    const int t = threadIdx.x;
    if (t == 0) smisc[0] = atomicAdd(ticket_ctr, 1);
    __syncthreads();
    const int tk   = smisc[0];
    const int b    = tk >> 8;                    // consecutive tickets = same batch
    const int tile = tk & (NTL - 1);
    const int l0   = tile * TL;

    // ---- stage x tile -> bf16 LDS (transposed [l][c]), the ONLY read of x ----
    const float* xb = x + (size_t)b * CC * LL + l0;
#pragma unroll
    for (int it = 0; it < 16; ++it) {
        const int idx = it * 256 + t;            // 0..4095
        const int l  = idx & 127;
        const int i0 = (idx >> 7) * 4;
        const float v0 = xb[(size_t)(i0 + 0) * LL + l];
        const float v1 = xb[(size_t)(i0 + 1) * LL + l];
        const float v2 = xb[(size_t)(i0 + 2) * LL + l];
        const float v3 = xb[(size_t)(i0 + 3) * LL + l];
        ushort4 u;
        u.x = f2bf(v0); u.y = f2bf(v1); u.z = f2bf(v2); u.w = f2bf(v3);
        *(ushort4*)&xlds[l * WROW + i0] = u;
    }
    __syncthreads();

    // ---- pool partials from the bf16 tile ----
    {
        const int c0 = (t & 31) * 4;
        const int lb = (t >> 5) * 16;
        float a0 = 0.f, a1 = 0.f, a2 = 0.f, a3 = 0.f;
#pragma unroll
        for (int j = 0; j < 16; ++j) {
            const ushort4 u = *(const ushort4*)&xlds[(lb + j) * WROW + c0];
            a0 += bf2f(u.x); a1 += bf2f(u.y); a2 += bf2f(u.z); a3 += bf2f(u.w);
        }
        scratch[(t >> 5) * 128 + c0 + 0] = a0;
        scratch[(t >> 5) * 128 + c0 + 1] = a1;
        scratch[(t >> 5) * 128 + c0 + 2] = a2;
        scratch[(t >> 5) * 128 + c0 + 3] = a3;
    }
    __syncthreads();
    if (t < CC) {
        float s = 0.f;
#pragma unroll
        for (int k = 0; k < 8; ++k) s += scratch[k * 128 + t];
        atomicAdd(&pool[b * CC + t], s);         // device-scope
    }

    // ---- W A-fragments -> registers (overlaps the wait; L2-hot) ----
    const int lane = t & 63;
    const int og   = t >> 6;
    const int m  = lane & 31;
    const int kh = lane >> 5;
    short8 wfrag[8];
    {
        const float* wr = conv_w + (og * 32 + m) * CC + kh * 8;
#pragma unroll
        for (int ks = 0; ks < 8; ++ks) {
            const float4 a = *(const float4*)(wr + ks * 16);
            const float4 c = *(const float4*)(wr + ks * 16 + 4);
            short8 f;
            f[0] = (short)f2bf(a.x); f[1] = (short)f2bf(a.y);
            f[2] = (short)f2bf(a.z); f[3] = (short)f2bf(a.w);
            f[4] = (short)f2bf(c.x); f[5] = (short)f2bf(c.y);
            f[6] = (short)f2bf(c.z); f[7] = (short)f2bf(c.w);
            wfrag[ks] = f;
        }
    }
    __syncthreads();   // drains pool atomics (vmcnt(0) before s_barrier)

    // ---- per-batch arrival + spin until all NTL tiles contributed ----
    if (t == 0) {
        atomicAdd(&counter[b], 1);
        volatile int* vc = counter + b;
        while (*vc < NTL) __builtin_amdgcn_s_sleep(10);
    }
    __syncthreads();

    // ---- gate: logits -> argmax -> per-channel affine (redundant per block) ----
    if (t < CC) {
        volatile float* vp = pool + b * CC;      // L1-bypass read of final sums
        scratch[t] = vp[t];
    }
    __syncthreads();
    if (t < GG) {
        float s = 0.f;
        for (int c = 0; c < CC; ++c) s += scratch[c] * w_gate[t * CC + c];
        scratch[512 + t] = s * (1.0f / LL) + gumbel[b * GG + t];
    }
    __syncthreads();
    if (t == 0) {
        int best = 0; float bv = scratch[512];
        for (int g = 1; g < GG; ++g)
            if (scratch[512 + g] > bv) { bv = scratch[512 + g]; best = g; }
        smisc[1] = best;
    }
    __syncthreads();
    {
        const int g = smisc[1];
        if (t < CC) {
            const int width = 32 * (g + 1);
            float a = 0.f, tt = 0.f;
            if (t < width) {
                const float inv = rsqrtf(rvar[g * CC + t] + EPSV);
                const float s = bn_w[t] * inv;
                a = s;
                tt = (conv_b[t] - rmean[g * CC + t]) * s + bn_b[t];
            }
            scratch[128 + t] = a;                // sA
            scratch[256 + t] = tt;               // sT
        }
    }
    __syncthreads();

    // ---- MFMA on the still-resident LDS tile ----
    f32x16 acc[4];
#pragma unroll
    for (int nt = 0; nt < 4; ++nt)
#pragma unroll
        for (int r = 0; r < 16; ++r) acc[nt][r] = 0.f;

#pragma unroll
    for (int ks = 0; ks < 8; ++ks) {
#pragma unroll
        for (int nt = 0; nt < 4; ++nt) {
            const short8 bf = *(const short8*)&xlds[(nt * 32 + m) * WROW + ks * 16 + kh * 8];
            acc[nt] = __builtin_amdgcn_mfma_f32_32x32x16_bf16(wfrag[ks], bf, acc[nt], 0, 0, 0);
        }
    }

    // ---- epilogue: affine + NT coalesced stores ----
    float sreg[16], treg[16];
#pragma unroll
    for (int r = 0; r < 16; ++r) {
        const int o = og * 32 + (r & 3) + 8 * (r >> 2) + 4 * kh;
        sreg[r] = scratch[128 + o]; treg[r] = scratch[256 + o];
    }
    float* ob = out + (size_t)b * CC * LL + l0;
#pragma unroll
    for (int nt = 0; nt < 4; ++nt) {
#pragma unroll
        for (int r = 0; r < 16; ++r) {
            const int o = og * 32 + (r & 3) + 8 * (r >> 2) + 4 * kh;
            __builtin_nontemporal_store(fmaf(acc[nt][r], sreg[r], treg[r]),
                                        ob + (size_t)o * LL + nt * 32 + m);
        }
    }
}

extern "C" void kernel_launch(void* const* d_in, const int* in_sizes, int n_in,
                              void* d_out, int out_size, void* d_ws, size_t ws_size,
                              hipStream_t stream) {
    const float* x      = (const float*)d_in[0];
    const float* gumbel = (const float*)d_in[1];
    const float* w_gate = (const float*)d_in[2];
    const float* conv_w = (const float*)d_in[3];
    const float* conv_b = (const float*)d_in[4];
    const float* bn_w   = (const float*)d_in[5];
    const float* bn_b   = (const float*)d_in[6];
    const float* rmean  = (const float*)d_in[7];
    const float* rvar   = (const float*)d_in[8];
    float* out = (float*)d_out;

    float* pool       = (float*)d_ws;                    // 2048 floats (sums)
    int*   counter    = (int*)(pool + BB * CC);          // 16 ints
    int*   ticket_ctr = counter + BB;                    // 1 int

    hipMemsetAsync(d_ws, 0, (BB * CC + BB + 1) * sizeof(int), stream);
    fused_kernel<<<BB * NTL, 256, 0, stream>>>(x, gumbel, w_gate, conv_b, bn_w,
                                               bn_b, rmean, rvar, conv_w,
                                               pool, counter, ticket_ctr, out);
}

// Round 9
// 141.747 us; speedup vs baseline: 4.3734x; 4.3734x over previous
//
#include <hip/hip_runtime.h>

#define CC   128      // channels
#define GG   4        // gates
#define BB   16       // batch
#define LL   32768    // length
#define TL   128      // l-positions per conv block
#define NTL  256      // l-tiles (LL/TL)
#define EPSV 1e-5f
#define WROW 136      // ushorts per LDS row = 272 B (breaks power-of-2 bank aliasing)

typedef short short8 __attribute__((ext_vector_type(8)));
typedef float f32x16 __attribute__((ext_vector_type(16)));
typedef float f32x4  __attribute__((ext_vector_type(4)));

__device__ inline unsigned short f2bf(float f) {   // RNE float->bf16
    union { float f; unsigned int u; } v; v.f = f;
    unsigned int r = (v.u + 0x7FFF + ((v.u >> 16) & 1)) >> 16;
    return (unsigned short)r;
}

// ---- Kernel 1: pool[b,c] = mean_l x[b,c,l]  AND  xb16 = bf16(x) ----
// Pure streaming: one (b,c) row per block, NT reads of x (never needed again;
// keep it OUT of L3), temporal writes of xb16 (we want it L3-resident for the
// conv pass). No atomics, single wave-reduce at the end.
__global__ __launch_bounds__(256) void prep_kernel(const float* __restrict__ x,
                                                   float* __restrict__ pool,
                                                   unsigned short* __restrict__ xb16) {
    const int row = blockIdx.x;                  // b*CC + c
    const f32x4* xr = (const f32x4*)(x + (size_t)row * LL);
    ushort4* yr = (ushort4*)(xb16 + (size_t)row * LL);
    const int t = threadIdx.x;
    float s = 0.f;
#pragma unroll
    for (int k = 0; k < (LL / 4) / 256; ++k) {   // 32 iterations
        const f32x4 v = __builtin_nontemporal_load(&xr[t + k * 256]);
        s += (v.x + v.y) + (v.z + v.w);
        ushort4 u;
        u.x = f2bf(v.x); u.y = f2bf(v.y); u.z = f2bf(v.z); u.w = f2bf(v.w);
        yr[t + k * 256] = u;
    }
    for (int off = 32; off > 0; off >>= 1) s += __shfl_down(s, off, 64);
    __shared__ float red[4];
    if ((t & 63) == 0) red[t >> 6] = s;
    __syncthreads();
    if (t == 0) pool[row] = (red[0] + red[1] + red[2] + red[3]) * (1.0f / LL);
}

// ------- Kernel 2: gate (argmax of logits+gumbel) -> per-(b,c) affine -------
__global__ __launch_bounds__(256) void gate_kernel(const float* __restrict__ pool,
                                                   const float* __restrict__ gumbel,
                                                   const float* __restrict__ w_gate,
                                                   const float* __restrict__ conv_b,
                                                   const float* __restrict__ bn_w,
                                                   const float* __restrict__ bn_b,
                                                   const float* __restrict__ rmean,
                                                   const float* __restrict__ rvar,
                                                   float* __restrict__ Acoef,
                                                   float* __restrict__ Tcoef) {
    __shared__ float yl[BB][GG];
    __shared__ int   sidx[BB];
    const int t = threadIdx.x;
    if (t < BB * GG) {
        const int b = t / GG, g = t % GG;
        float s = 0.f;
        for (int c = 0; c < CC; ++c) s += pool[b * CC + c] * w_gate[g * CC + c];
        yl[b][g] = s + gumbel[b * GG + g];
    }
    __syncthreads();
    if (t < BB) {
        int best = 0; float bv = yl[t][0];
        for (int g = 1; g < GG; ++g) { if (yl[t][g] > bv) { bv = yl[t][g]; best = g; } }
        sidx[t] = best;
    }
    __syncthreads();
    for (int i = t; i < BB * CC; i += 256) {
        const int b = i / CC, c = i % CC;
        const int g = sidx[b];
        const int width = 32 * (g + 1);
        float a = 0.f, tt = 0.f;
        if (c < width) {
            const float inv = rsqrtf(rvar[g * CC + c] + EPSV);
            const float s = bn_w[c] * inv;
            a = s;
            tt = (conv_b[c] - rmean[g * CC + c]) * s + bn_b[c];
        }
        Acoef[i] = a;
        Tcoef[i] = tt;
    }
}

// ------- Kernel 3 (MFMA): reads bf16 xb16 (half the bytes, L3-candidate) -------
__global__ __launch_bounds__(256, 4) void conv_kernel(const unsigned short* __restrict__ xb16,
                                                      const float* __restrict__ conv_w,
                                                      const float* __restrict__ Acoef,
                                                      const float* __restrict__ Tcoef,
                                                      float* __restrict__ out) {
    __shared__ unsigned short xlds[TL * WROW];   // 34,816 B
    __shared__ float sA[CC], sT[CC];

    const int b  = blockIdx.y;
    const int l0 = blockIdx.x * TL;
    const int t  = threadIdx.x;
    const int lane = t & 63;
    const int og   = t >> 6;
    const int m  = lane & 31;
    const int kh = lane >> 5;     // 0/1: which k-half of the fragment

    if (t < CC) { sA[t] = Acoef[b * CC + t]; sT[t] = Tcoef[b * CC + t]; }

    // ---- W A-fragments -> registers: lane (m,kh) holds W[og*32+m][ks*16+kh*8 .. +7] ----
    short8 wfrag[8];
    {
        const float* wr = conv_w + (og * 32 + m) * CC + kh * 8;
#pragma unroll
        for (int ks = 0; ks < 8; ++ks) {
            const float4 a = *(const float4*)(wr + ks * 16);
            const float4 c = *(const float4*)(wr + ks * 16 + 4);
            short8 f;
            f[0] = (short)f2bf(a.x); f[1] = (short)f2bf(a.y);
            f[2] = (short)f2bf(a.z); f[3] = (short)f2bf(a.w);
            f[4] = (short)f2bf(c.x); f[5] = (short)f2bf(c.y);
            f[6] = (short)f2bf(c.z); f[7] = (short)f2bf(c.w);
            wfrag[ks] = f;
        }
    }

    // ---- stage xb16 tile transposed -> xT[l][i], rows of 272 B ----
    const unsigned short* xb = xb16 + (size_t)b * CC * LL + l0;
#pragma unroll
    for (int it = 0; it < 16; ++it) {
        const int idx = it * 256 + t;            // 0..4095
        const int l  = idx & 127;
        const int i0 = (idx >> 7) * 4;
        ushort4 u;
        u.x = xb[(size_t)(i0 + 0) * LL + l];
        u.y = xb[(size_t)(i0 + 1) * LL + l];
        u.z = xb[(size_t)(i0 + 2) * LL + l];
        u.w = xb[(size_t)(i0 + 3) * LL + l];
        *(ushort4*)&xlds[l * WROW + i0] = u;
    }
    __syncthreads();

    // ---- MFMA K-loop: 8 k-steps of 16, 4 n-tiles of 32 ----
    f32x16 acc[4];
#pragma unroll
    for (int nt = 0; nt < 4; ++nt)
#pragma unroll
        for (int r = 0; r < 16; ++r) acc[nt][r] = 0.f;

#pragma unroll
    for (int ks = 0; ks < 8; ++ks) {
#pragma unroll
        for (int nt = 0; nt < 4; ++nt) {
            const short8 bf = *(const short8*)&xlds[(nt * 32 + m) * WROW + ks * 16 + kh * 8];
            acc[nt] = __builtin_amdgcn_mfma_f32_32x32x16_bf16(wfrag[ks], bf, acc[nt], 0, 0, 0);
        }
    }

    // ---- epilogue: per-(b,o) affine, non-temporal coalesced stores ----
    float sreg[16], treg[16];
#pragma unroll
    for (int r = 0; r < 16; ++r) {
        const int o = og * 32 + (r & 3) + 8 * (r >> 2) + 4 * kh;
        sreg[r] = sA[o]; treg[r] = sT[o];
    }
    float* ob = out + (size_t)b * CC * LL + l0;
#pragma unroll
    for (int nt = 0; nt < 4; ++nt) {
#pragma unroll
        for (int r = 0; r < 16; ++r) {
            const int o = og * 32 + (r & 3) + 8 * (r >> 2) + 4 * kh;
            __builtin_nontemporal_store(fmaf(acc[nt][r], sreg[r], treg[r]),
                                        ob + (size_t)o * LL + nt * 32 + m);
        }
    }
}

extern "C" void kernel_launch(void* const* d_in, const int* in_sizes, int n_in,
                              void* d_out, int out_size, void* d_ws, size_t ws_size,
                              hipStream_t stream) {
    const float* x      = (const float*)d_in[0];
    const float* gumbel = (const float*)d_in[1];
    const float* w_gate = (const float*)d_in[2];
    const float* conv_w = (const float*)d_in[3];
    const float* conv_b = (const float*)d_in[4];
    const float* bn_w   = (const float*)d_in[5];
    const float* bn_b   = (const float*)d_in[6];
    const float* rmean  = (const float*)d_in[7];
    const float* rvar   = (const float*)d_in[8];
    float* out = (float*)d_out;

    float* pool  = (float*)d_ws;                              // 2048 floats
    float* Acoef = pool + BB * CC;
    float* Tcoef = Acoef + BB * CC;
    unsigned short* xb16 = (unsigned short*)((char*)d_ws + 65536);  // 128 MiB

    prep_kernel<<<BB * CC, 256, 0, stream>>>(x, pool, xb16);
    gate_kernel<<<1, 256, 0, stream>>>(pool, gumbel, w_gate, conv_b, bn_w, bn_b,
                                       rmean, rvar, Acoef, Tcoef);
    conv_kernel<<<dim3(NTL, BB), 256, 0, stream>>>(xb16, conv_w, Acoef, Tcoef, out);
}